// Round 1
// baseline (259.068 us; speedup 1.0000x reference)
//
#include <hip/hip_runtime.h>
#include <math.h>

#define NNODES  100000
#define NEDGES  3200000
#define NGRAPHS 1024
#define BNODES  196                              // nodes per bucket
#define NBUCK   ((NNODES + BNODES - 1) / BNODES) // 511
#define SCAP    12288                            // staging capacity per bucket
#define CHUNK   4096
#define NCHUNKS ((NEDGES + CHUNK - 1) / CHUNK)   // 782

typedef int iv4 __attribute__((ext_vector_type(4)));
typedef float fv2 __attribute__((ext_vector_type(2)));

#if defined(__has_builtin)
#if __has_builtin(__builtin_amdgcn_cvt_pk_f32_fp8) && __has_builtin(__builtin_amdgcn_cvt_pk_fp8_f32)
#define HW_FP8 1
#endif
#endif

// ---- bf16x2 pack/unpack (RNE) ----
__device__ __forceinline__ unsigned bf16pair(float a, float b) {
    unsigned ua = __float_as_uint(a), ub = __float_as_uint(b);
    ua += 0x7fffu + ((ua >> 16) & 1u);
    ub += 0x7fffu + ((ub >> 16) & 1u);
    return (ua >> 16) | (ub & 0xffff0000u);
}
__device__ __forceinline__ float bflo(unsigned u) { return __uint_as_float(u << 16); }
__device__ __forceinline__ float bfhi(unsigned u) { return __uint_as_float(u & 0xffff0000u); }

// ---- fp8 e4m3 (OCP) manual fallback ----
__device__ __forceinline__ unsigned fp8_of(float v) {
    unsigned s = (__float_as_uint(v) >> 24) & 0x80u;
    float a = fminf(fabsf(v), 448.f);
    unsigned ub = __float_as_uint(a);
    unsigned lsb = (ub >> 20) & 1u;
    ub += 0x0007FFFFu + lsb;
    int em = (int)(ub >> 20) - (120 << 3);
    if (em < 1) return s;
    if (em > 0x7E) em = 0x7E;
    return s | (unsigned)em;
}
__device__ __forceinline__ float fp8_to_f(unsigned b) {
    unsigned em = b & 0x7Fu;
    unsigned s = (b & 0x80u) << 24;
    float f = __uint_as_float(s | ((em + 0x3C0u) << 20));
    return (em >= 8u) ? f : 0.f;
}
__device__ __forceinline__ unsigned fp8x4_pack(float a, float b, float c, float d) {
    a = fminf(fmaxf(a, -448.f), 448.f);
    b = fminf(fmaxf(b, -448.f), 448.f);
    c = fminf(fmaxf(c, -448.f), 448.f);
    d = fminf(fmaxf(d, -448.f), 448.f);
#ifdef HW_FP8
    int w = __builtin_amdgcn_cvt_pk_fp8_f32(a, b, 0, false);
    w = __builtin_amdgcn_cvt_pk_fp8_f32(c, d, w, true);
    return (unsigned)w;
#else
    return fp8_of(a) | (fp8_of(b) << 8) | (fp8_of(c) << 16) | (fp8_of(d) << 24);
#endif
}
__device__ __forceinline__ fv2 f8lo(unsigned w) {
#ifdef HW_FP8
    return __builtin_amdgcn_cvt_pk_f32_fp8((int)w, false);
#else
    fv2 t; t.x = fp8_to_f(w & 0xFFu); t.y = fp8_to_f((w >> 8) & 0xFFu); return t;
#endif
}
__device__ __forceinline__ fv2 f8hi(unsigned w) {
#ifdef HW_FP8
    return __builtin_amdgcn_cvt_pk_f32_fp8((int)w, true);
#else
    fv2 t; t.x = fp8_to_f((w >> 16) & 0xFFu); t.y = fp8_to_f(w >> 24); return t;
#endif
}

// ---------------- init ----------------

__global__ void zero4_kernel(int4* p, int nvec) {
    int i = blockIdx.x * blockDim.x + threadIdx.x;
    if (i < nvec) p[i] = make_int4(0, 0, 0, 0);
}

// ---------------- binA: LDS-staged bucket sort with ordered copy ----------------

__global__ void binA_kernel(const int* __restrict__ src, const int* __restrict__ dst,
                            int* __restrict__ bucketCur, int* __restrict__ stage) {
    __shared__ int lcnt[NBUCK + 1];
    __shared__ int boff[NBUCK + 1];
    __shared__ int gbase[NBUCK + 1];
    __shared__ int cur[NBUCK + 1];
    __shared__ int ssum[256];
    __shared__ int packed[CHUNK];
    __shared__ unsigned short bof[CHUNK];
    int tid = threadIdx.x;
    int beg = blockIdx.x * CHUNK;
    int end = beg + CHUNK; if (end > NEDGES) end = NEDGES;
    int cnt = end - beg;

    for (int i = tid; i <= NBUCK; i += 256) lcnt[i] = 0;
    __syncthreads();

    int ent[16];
    int bk[16];
#pragma unroll
    for (int it = 0; it < 4; ++it) {
        int e0 = beg + tid * 4 + it * 1024;
        if (e0 < end) {
            iv4 d4 = __builtin_nontemporal_load((const iv4*)(dst + e0));
            iv4 s4 = __builtin_nontemporal_load((const iv4*)(src + e0));
            int b;
            b = d4.x / BNODES; ent[it*4+0] = s4.x | ((d4.x - b*BNODES) << 17); bk[it*4+0] = b; atomicAdd(&lcnt[b], 1);
            b = d4.y / BNODES; ent[it*4+1] = s4.y | ((d4.y - b*BNODES) << 17); bk[it*4+1] = b; atomicAdd(&lcnt[b], 1);
            b = d4.z / BNODES; ent[it*4+2] = s4.z | ((d4.z - b*BNODES) << 17); bk[it*4+2] = b; atomicAdd(&lcnt[b], 1);
            b = d4.w / BNODES; ent[it*4+3] = s4.w | ((d4.w - b*BNODES) << 17); bk[it*4+3] = b; atomicAdd(&lcnt[b], 1);
        } else {
            bk[it*4+0] = -1; bk[it*4+1] = -1; bk[it*4+2] = -1; bk[it*4+3] = -1;
            ent[it*4+0] = 0; ent[it*4+1] = 0; ent[it*4+2] = 0; ent[it*4+3] = 0;
        }
    }
    __syncthreads();

    int b0 = 2 * tid, b1 = 2 * tid + 1;
    int c0 = lcnt[b0];
    int c1 = (b1 < NBUCK) ? lcnt[b1] : 0;
    int sum = c0 + c1;
    ssum[tid] = sum;
    __syncthreads();
    for (int o = 1; o < 256; o <<= 1) {
        int t = (tid >= o) ? ssum[tid - o] : 0;
        __syncthreads();
        ssum[tid] += t;
        __syncthreads();
    }
    int excl = ssum[tid] - sum;
    boff[b0] = excl; cur[b0] = excl;
    if (b1 < NBUCK) { boff[b1] = excl + c0; cur[b1] = excl + c0; }
    if (c0 > 0) gbase[b0] = atomicAdd(&bucketCur[b0], c0);
    if (b1 < NBUCK && c1 > 0) gbase[b1] = atomicAdd(&bucketCur[b1], c1);
    __syncthreads();

#pragma unroll
    for (int k = 0; k < 16; ++k) {
        int b = bk[k];
        if (b >= 0) {
            int p = atomicAdd(&cur[b], 1);
            packed[p] = ent[k];
            bof[p] = (unsigned short)b;
        }
    }
    __syncthreads();

    for (int i = tid; i < cnt; i += 256) {
        int b = bof[i];
        int addr = b * SCAP + gbase[b] + (i - boff[b]);
        stage[addr] = packed[i];
    }
}

// ---------------- scanE ----------------

__global__ void scanE_kernel(const int* __restrict__ bucketCur, int* __restrict__ ebase) {
    int lane = threadIdx.x;          // 64 lanes
    int run = 0;
    for (int base = 0; base < NBUCK; base += 64) {
        int idx = base + lane;
        int own = (idx < NBUCK) ? bucketCur[idx] : 0;
        int v = own;
        for (int o = 1; o < 64; o <<= 1) {
            int t = __shfl_up(v, o, 64);
            if (lane >= o) v += t;
        }
        if (idx < NBUCK) ebase[idx] = run + v - own;
        run += __shfl(v, 63, 64);
    }
}

// ---------------- binB: per-bucket fine sort + rowptr/rowend/dinv/xs ----------------

__global__ void binB_kernel(const int* __restrict__ bucketCur, const int* __restrict__ ebase,
                            const int* __restrict__ stage, const float2* __restrict__ x,
                            int* __restrict__ entries, int* __restrict__ rowptr,
                            int* __restrict__ rowend, float* __restrict__ dinv,
                            unsigned* __restrict__ xs) {
    __shared__ int s[256];
    __shared__ int ncur[256];
    __shared__ float ndinv[256];
    int b = blockIdx.x;
    int cntE = bucketCur[b];
    int eb = ebase[b];
    int nlo = b * BNODES;
    int nn = NNODES - nlo; if (nn > BNODES) nn = BNODES;
    int sb = b * SCAP;
    int tid = threadIdx.x;

    s[tid] = 0;
    __syncthreads();
    for (int e = tid; e < cntE; e += 256) {
        unsigned w = (unsigned)stage[sb + e];
        atomicAdd(&s[w >> 17], 1);
    }
    __syncthreads();
    int v = s[tid];
    for (int o = 1; o < 256; o <<= 1) {
        int t = (tid >= o) ? s[tid - o] : 0;
        __syncthreads();
        s[tid] += t;
        __syncthreads();
    }
    int excl = s[tid] - v;
    ncur[tid] = excl;
    if (tid < nn) {
        rowptr[nlo + tid] = eb + excl;
        rowend[nlo + tid] = eb + excl + v;
        float di = rsqrtf((float)(v + 1));   // +1 self-loop
        dinv[nlo + tid] = di;
        ndinv[tid] = di;
    }
    __syncthreads();
    for (int i = tid; i < nn * 8; i += 256) {
        int node = i >> 3, w = i & 7;
        float2 v2 = x[(size_t)(nlo + node) * 8 + w];
        float di = ndinv[node];
        xs[(nlo + node) * 8 + w] = bf16pair(v2.x * di, v2.y * di);
    }
    for (int e = tid; e < cntE; e += 256) {
        unsigned w = (unsigned)stage[sb + e];
        int dl = w >> 17;
        int slot = atomicAdd(&ncur[dl], 1);
        entries[eb + slot] = (int)(w & 0x1FFFFu);
    }
}

// ---------------- gather layer 1: 2 lanes/node, 16B gathers, no shuffles ----------------

__device__ __forceinline__ void acc_bf(unsigned u, fv2& a) {
    fv2 t; t.x = bflo(u); t.y = bfhi(u);
    a += t;
}
#define ACCX4(V) { acc_bf((V).x, acc0); acc_bf((V).y, acc1); acc_bf((V).z, acc2); acc_bf((V).w, acc3); }

__global__ void __launch_bounds__(256) gatherX_kernel(const int* __restrict__ entries,
        const int* __restrict__ rowptr, const int* __restrict__ rowend,
        const float* __restrict__ dinv, const uint4* __restrict__ xsv,
        float4* __restrict__ agg) {
    int t = blockIdx.x * 256 + threadIdx.x;
    int n = t >> 1, half = t & 1;
    if (n >= NNODES) return;
    int beg = rowptr[n], end = rowend[n];
    uint4 sv = xsv[n * 2 + half];
    fv2 acc0, acc1, acc2, acc3;
    acc0.x = bflo(sv.x); acc0.y = bfhi(sv.x);
    acc1.x = bflo(sv.y); acc1.y = bfhi(sv.y);
    acc2.x = bflo(sv.z); acc2.y = bfhi(sv.z);
    acc3.x = bflo(sv.w); acc3.y = bfhi(sv.w);

    int p = beg;
    iv4 e0 = {0,0,0,0}, e1 = {0,0,0,0};
    bool have = (p + 8 <= end);
    if (have) {
        __builtin_memcpy(&e0, entries + p, 16);
        __builtin_memcpy(&e1, entries + p + 4, 16);
    }
    while (have) {
        int np = p + 8;
        bool nhave = (np + 8 <= end);
        iv4 f0 = e0, f1 = e1;
        if (nhave) {
            __builtin_memcpy(&f0, entries + np, 16);
            __builtin_memcpy(&f1, entries + np + 4, 16);
        }
        uint4 v0 = xsv[e0.x * 2 + half];
        uint4 v1 = xsv[e0.y * 2 + half];
        uint4 v2 = xsv[e0.z * 2 + half];
        uint4 v3 = xsv[e0.w * 2 + half];
        uint4 v4 = xsv[e1.x * 2 + half];
        uint4 v5 = xsv[e1.y * 2 + half];
        uint4 v6 = xsv[e1.z * 2 + half];
        uint4 v7 = xsv[e1.w * 2 + half];
        ACCX4(v0); ACCX4(v1); ACCX4(v2); ACCX4(v3);
        ACCX4(v4); ACCX4(v5); ACCX4(v6); ACCX4(v7);
        e0 = f0; e1 = f1; p = np; have = nhave;
    }
    while (p < end) {
        int e = entries[p++];
        uint4 v = xsv[e * 2 + half];
        ACCX4(v);
    }
    float di = dinv[n];
    float4 o0, o1;
    o0.x = acc0.x * di; o0.y = acc0.y * di; o0.z = acc1.x * di; o0.w = acc1.y * di;
    o1.x = acc2.x * di; o1.y = acc2.y * di; o1.z = acc3.x * di; o1.w = acc3.y * di;
    agg[n * 4 + half * 2 + 0] = o0;
    agg[n * 4 + half * 2 + 1] = o1;
}

// ---------------- node MLP (separate, float4 LDS access) ----------------

__global__ void __launch_bounds__(256) mlp_kernel(const float4* __restrict__ agg,
        const float* __restrict__ dinv,
        const float* __restrict__ W1, const float* __restrict__ b1,
        const float* __restrict__ W2, unsigned* __restrict__ hm2f) {
    __shared__ __align__(16) float w1s[16 * 64];   // 4 KB
    __shared__ __align__(16) float w2s[64 * 32];   // 8 KB
    __shared__ float bb1[64];
    __shared__ __align__(16) float h1s[32][68];    // 8.5 KB, pad 68 keeps f4 align + spread
    int tid = threadIdx.x;
    for (int i = tid; i < 16 * 64; i += 256) w1s[i] = W1[i];
    for (int i = tid; i < 64 * 32; i += 256) w2s[i] = W2[i];
    if (tid < 64) bb1[tid] = b1[tid];

    int nl = tid >> 3, lane = tid & 7;
    int n = blockIdx.x * 32 + nl;
    const float4* ag = agg + n * 4;
    float4 A0 = ag[0], A1 = ag[1], A2 = ag[2], A3 = ag[3];
    float a[16] = {A0.x, A0.y, A0.z, A0.w, A1.x, A1.y, A1.z, A1.w,
                   A2.x, A2.y, A2.z, A2.w, A3.x, A3.y, A3.z, A3.w};
    __syncthreads();

    // phase B: h1[j] for j = lane*8 .. +7
    {
        int j0 = lane * 8;
        float h[8];
#pragma unroll
        for (int jj = 0; jj < 8; ++jj) h[jj] = bb1[j0 + jj];
#pragma unroll
        for (int k = 0; k < 16; ++k) {
            const float4* wr = (const float4*)(w1s + k * 64 + j0);
            float4 wa = wr[0], wb = wr[1];
            float av = a[k];
            h[0] += av * wa.x; h[1] += av * wa.y; h[2] += av * wa.z; h[3] += av * wa.w;
            h[4] += av * wb.x; h[5] += av * wb.y; h[6] += av * wb.z; h[7] += av * wb.w;
        }
        float4 r0, r1;
        r0.x = fmaxf(h[0], 0.f); r0.y = fmaxf(h[1], 0.f); r0.z = fmaxf(h[2], 0.f); r0.w = fmaxf(h[3], 0.f);
        r1.x = fmaxf(h[4], 0.f); r1.y = fmaxf(h[5], 0.f); r1.z = fmaxf(h[6], 0.f); r1.w = fmaxf(h[7], 0.f);
        float4* hw = (float4*)(&h1s[nl][j0]);
        hw[0] = r0; hw[1] = r1;
    }
    __syncthreads();

    // phase C: h2[j] for j = lane*4 .. +3, pack fp8 word (strict FMA order preserved)
    {
        int j0 = lane * 4;
        float c0 = 0.f, c1 = 0.f, c2 = 0.f, c3 = 0.f;
#pragma unroll
        for (int k = 0; k < 64; k += 4) {
            float4 hv = *(const float4*)(&h1s[nl][k]);
            float4 w0 = *(const float4*)(w2s + (k + 0) * 32 + j0);
            float4 w1v = *(const float4*)(w2s + (k + 1) * 32 + j0);
            float4 w2v = *(const float4*)(w2s + (k + 2) * 32 + j0);
            float4 w3 = *(const float4*)(w2s + (k + 3) * 32 + j0);
            c0 += hv.x * w0.x; c1 += hv.x * w0.y; c2 += hv.x * w0.z; c3 += hv.x * w0.w;
            c0 += hv.y * w1v.x; c1 += hv.y * w1v.y; c2 += hv.y * w1v.z; c3 += hv.y * w1v.w;
            c0 += hv.z * w2v.x; c1 += hv.z * w2v.y; c2 += hv.z * w2v.z; c3 += hv.z * w2v.w;
            c0 += hv.w * w3.x; c1 += hv.w * w3.y; c2 += hv.w * w3.z; c3 += hv.w * w3.w;
        }
        float sc = dinv[n] * 64.f;                  // x64 pre-scale for fp8
        hm2f[n * 8 + lane] = fp8x4_pack(c0 * sc, c1 * sc, c2 * sc, c3 * sc);
    }
}

// ---------------- gather layer 2 + pool: 2 lanes/node, 16B fp8 gathers ----------------

#define ACCH4(V) { q0lo += f8lo((V).x); q0hi += f8hi((V).x); \
                   q1lo += f8lo((V).y); q1hi += f8hi((V).y); \
                   q2lo += f8lo((V).z); q2hi += f8hi((V).z); \
                   q3lo += f8lo((V).w); q3hi += f8hi((V).w); }

__global__ void __launch_bounds__(256) gatherH_pool_kernel(const int* __restrict__ entries,
        const int* __restrict__ rowptr, const int* __restrict__ rowend,
        const float* __restrict__ dinv, const uint4* __restrict__ hm4,
        const float4* __restrict__ b2, const int* __restrict__ batch,
        float* __restrict__ psum, float* __restrict__ pcnt) {
    __shared__ float lps[8][32];
    __shared__ float lpc[8];
    int tid = threadIdx.x;
    ((float*)lps)[tid] = 0.f;
    if (tid < 8) lpc[tid] = 0.f;
    __syncthreads();

    int t = blockIdx.x * 256 + tid;
    int n = t >> 1, half = t & 1;
    int g0 = batch[(blockIdx.x * 256) >> 1];
    if (n < NNODES) {
        int beg = rowptr[n], end = rowend[n];
        uint4 sv = hm4[n * 2 + half];
        fv2 q0lo = f8lo(sv.x), q0hi = f8hi(sv.x);
        fv2 q1lo = f8lo(sv.y), q1hi = f8hi(sv.y);
        fv2 q2lo = f8lo(sv.z), q2hi = f8hi(sv.z);
        fv2 q3lo = f8lo(sv.w), q3hi = f8hi(sv.w);

        int p = beg;
        iv4 e0 = {0,0,0,0}, e1 = {0,0,0,0};
        bool have = (p + 8 <= end);
        if (have) {
            __builtin_memcpy(&e0, entries + p, 16);
            __builtin_memcpy(&e1, entries + p + 4, 16);
        }
        while (have) {
            int np = p + 8;
            bool nhave = (np + 8 <= end);
            iv4 f0 = e0, f1 = e1;
            if (nhave) {
                __builtin_memcpy(&f0, entries + np, 16);
                __builtin_memcpy(&f1, entries + np + 4, 16);
            }
            uint4 v0 = hm4[e0.x * 2 + half];
            uint4 v1 = hm4[e0.y * 2 + half];
            uint4 v2 = hm4[e0.z * 2 + half];
            uint4 v3 = hm4[e0.w * 2 + half];
            uint4 v4 = hm4[e1.x * 2 + half];
            uint4 v5 = hm4[e1.y * 2 + half];
            uint4 v6 = hm4[e1.z * 2 + half];
            uint4 v7 = hm4[e1.w * 2 + half];
            ACCH4(v0); ACCH4(v1); ACCH4(v2); ACCH4(v3);
            ACCH4(v4); ACCH4(v5); ACCH4(v6); ACCH4(v7);
            e0 = f0; e1 = f1; p = np; have = nhave;
        }
        while (p < end) {
            int e = entries[p++];
            uint4 v = hm4[e * 2 + half];
            ACCH4(v);
        }

        float sc = dinv[n] * (1.0f / 64.f);         // undo x64 pre-scale
        float4 bv0 = b2[half * 4 + 0], bv1 = b2[half * 4 + 1],
               bv2 = b2[half * 4 + 2], bv3 = b2[half * 4 + 3];
        float vv[16];
        vv[0]  = fmaxf(q0lo.x * sc + bv0.x, 0.f);
        vv[1]  = fmaxf(q0lo.y * sc + bv0.y, 0.f);
        vv[2]  = fmaxf(q0hi.x * sc + bv0.z, 0.f);
        vv[3]  = fmaxf(q0hi.y * sc + bv0.w, 0.f);
        vv[4]  = fmaxf(q1lo.x * sc + bv1.x, 0.f);
        vv[5]  = fmaxf(q1lo.y * sc + bv1.y, 0.f);
        vv[6]  = fmaxf(q1hi.x * sc + bv1.z, 0.f);
        vv[7]  = fmaxf(q1hi.y * sc + bv1.w, 0.f);
        vv[8]  = fmaxf(q2lo.x * sc + bv2.x, 0.f);
        vv[9]  = fmaxf(q2lo.y * sc + bv2.y, 0.f);
        vv[10] = fmaxf(q2hi.x * sc + bv2.z, 0.f);
        vv[11] = fmaxf(q2hi.y * sc + bv2.w, 0.f);
        vv[12] = fmaxf(q3lo.x * sc + bv3.x, 0.f);
        vv[13] = fmaxf(q3lo.y * sc + bv3.y, 0.f);
        vv[14] = fmaxf(q3hi.x * sc + bv3.z, 0.f);
        vv[15] = fmaxf(q3hi.y * sc + bv3.w, 0.f);

        int g = batch[n], gr = g - g0;
        if (gr < 8) {
            float* pg = &lps[gr][half * 16];
#pragma unroll
            for (int k2 = 0; k2 < 16; ++k2) atomicAdd(pg + k2, vv[k2]);
            if (half == 0) atomicAdd(&lpc[gr], 1.0f);
        } else {
            float* pg = psum + g * 32 + half * 16;
#pragma unroll
            for (int k2 = 0; k2 < 16; ++k2) atomicAdd(pg + k2, vv[k2]);
            if (half == 0) atomicAdd(&pcnt[g], 1.0f);
        }
    }
    __syncthreads();
    int grf = tid >> 5, f = tid & 31;
    float v = lps[grf][f];
    if (v != 0.f) atomicAdd(&psum[(g0 + grf) * 32 + f], v);
    if (f == 0) {
        float c = lpc[grf];
        if (c != 0.f) atomicAdd(&pcnt[g0 + grf], c);
    }
}

// ---------------- head ----------------

__global__ void head_kernel(const float* __restrict__ psum, const float* __restrict__ pcnt,
                            const float* __restrict__ fc1W, const float* __restrict__ fc1b,
                            const float* __restrict__ fc2W, const float* __restrict__ fc2b,
                            float* __restrict__ out) {
    int g = blockIdx.x * blockDim.x + threadIdx.x;
    if (g >= NGRAPHS) return;
    float inv = 1.0f / fmaxf(pcnt[g], 1.0f);
    float gv[32];
#pragma unroll
    for (int k = 0; k < 32; ++k) gv[k] = psum[g * 32 + k] * inv;
    float o = fc2b[0];
#pragma unroll
    for (int j = 0; j < 16; ++j) {
        float h = fc1b[j];
#pragma unroll
        for (int k = 0; k < 32; ++k) h += gv[k] * fc1W[k * 16 + j];
        h = fmaxf(h, 0.f);
        o += h * fc2W[j];
    }
    out[g] = 1.0f / (1.0f + expf(-o));
}

// ---------------- launch ----------------

extern "C" void kernel_launch(void* const* d_in, const int* in_sizes, int n_in,
                              void* d_out, int out_size, void* d_ws, size_t ws_size,
                              hipStream_t stream) {
    const float* x    = (const float*)d_in[0];
    const int*   ei   = (const int*)d_in[1];
    const int*   batch= (const int*)d_in[2];
    const float* W1   = (const float*)d_in[3];
    const float* b1   = (const float*)d_in[4];
    const float* W2   = (const float*)d_in[5];
    const float* b2   = (const float*)d_in[6];
    const float* fc1W = (const float*)d_in[7];
    const float* fc1b = (const float*)d_in[8];
    const float* fc2W = (const float*)d_in[9];
    const float* fc2b = (const float*)d_in[10];
    float* out = (float*)d_out;

    const int* src = ei;
    const int* dst = ei + NEDGES;

    char* wsb = (char*)d_ws;
    int*      bucketCur = (int*)wsb;                 // 2048 B  } zeroed span
    float*    psum      = (float*)(wsb + 2048);      // 131072  }
    float*    pcnt      = (float*)(wsb + 133120);    // 4096    }  -> zero 137216 B
    int*      ebase     = (int*)(wsb + 137216);      // 2048
    float*    dinv      = (float*)(wsb + 139264);    // 400000
    int*      rowptr    = (int*)(wsb + 539264);      // 400000
    int*      rowend    = (int*)(wsb + 939264);      // 400000
    int*      stage     = (int*)(wsb + 1339392);     // 25.1 MB
    int*      entries   = (int*)(wsb + 26456064);    // 12.8 MB
    unsigned* xs        = (unsigned*)(wsb + 39256064);   // 3.2 MB (bf16x2)
    unsigned* hm2f      = (unsigned*)(wsb + 42456064);   // 3.2 MB (fp8, 32 B rows)
    // agg (f32 layer-1 aggregate, 6.4 MB) aliases stage — stage is dead after binB
    float4*   agg       = (float4*)(wsb + 1339392);

    const int B = 256;
    zero4_kernel<<<(8576 + B - 1) / B, B, 0, stream>>>((int4*)wsb, 8576);

    binA_kernel<<<NCHUNKS, B, 0, stream>>>(src, dst, bucketCur, stage);
    scanE_kernel<<<1, 64, 0, stream>>>(bucketCur, ebase);
    binB_kernel<<<NBUCK, B, 0, stream>>>(bucketCur, ebase, stage, (const float2*)x,
                                         entries, rowptr, rowend, dinv, xs);

    const int GTH = (2 * NNODES + B - 1) / B;        // 782
    gatherX_kernel<<<GTH, B, 0, stream>>>(entries, rowptr, rowend, dinv,
                                          (const uint4*)xs, agg);
    mlp_kernel<<<NNODES / 32, B, 0, stream>>>((const float4*)agg, dinv, W1, b1, W2, hm2f);
    gatherH_pool_kernel<<<GTH, B, 0, stream>>>(entries, rowptr, rowend, dinv,
                                               (const uint4*)hm2f, (const float4*)b2,
                                               batch, psum, pcnt);
    head_kernel<<<(NGRAPHS + B - 1) / B, B, 0, stream>>>(psum, pcnt, fc1W, fc1b, fc2W, fc2b, out);
}

// Round 2
// 242.707 us; speedup vs baseline: 1.0674x; 1.0674x over previous
//
#include <hip/hip_runtime.h>
#include <math.h>

#define NNODES  100000
#define NEDGES  3200000
#define NGRAPHS 1024
#define BNODES  196                              // nodes per bucket
#define NBUCK   ((NNODES + BNODES - 1) / BNODES) // 511
#define SCAP    12288                            // staging capacity per bucket
#define CHUNK   4096
#define NCHUNKS ((NEDGES + CHUNK - 1) / CHUNK)   // 782

typedef int iv4 __attribute__((ext_vector_type(4)));
typedef float fv2 __attribute__((ext_vector_type(2)));

#if defined(__has_builtin)
#if __has_builtin(__builtin_amdgcn_cvt_pk_f32_fp8) && __has_builtin(__builtin_amdgcn_cvt_pk_fp8_f32)
#define HW_FP8 1
#endif
#endif

// ---- bf16x2 pack/unpack (RNE) ----
__device__ __forceinline__ unsigned bf16pair(float a, float b) {
    unsigned ua = __float_as_uint(a), ub = __float_as_uint(b);
    ua += 0x7fffu + ((ua >> 16) & 1u);
    ub += 0x7fffu + ((ub >> 16) & 1u);
    return (ua >> 16) | (ub & 0xffff0000u);
}
__device__ __forceinline__ float bflo(unsigned u) { return __uint_as_float(u << 16); }
__device__ __forceinline__ float bfhi(unsigned u) { return __uint_as_float(u & 0xffff0000u); }

// ---- fp8 e4m3 (OCP) manual fallback ----
__device__ __forceinline__ unsigned fp8_of(float v) {
    unsigned s = (__float_as_uint(v) >> 24) & 0x80u;
    float a = fminf(fabsf(v), 448.f);
    unsigned ub = __float_as_uint(a);
    unsigned lsb = (ub >> 20) & 1u;
    ub += 0x0007FFFFu + lsb;
    int em = (int)(ub >> 20) - (120 << 3);
    if (em < 1) return s;
    if (em > 0x7E) em = 0x7E;
    return s | (unsigned)em;
}
__device__ __forceinline__ float fp8_to_f(unsigned b) {
    unsigned em = b & 0x7Fu;
    unsigned s = (b & 0x80u) << 24;
    float f = __uint_as_float(s | ((em + 0x3C0u) << 20));
    return (em >= 8u) ? f : 0.f;
}
__device__ __forceinline__ unsigned fp8x4_pack(float a, float b, float c, float d) {
    a = fminf(fmaxf(a, -448.f), 448.f);
    b = fminf(fmaxf(b, -448.f), 448.f);
    c = fminf(fmaxf(c, -448.f), 448.f);
    d = fminf(fmaxf(d, -448.f), 448.f);
#ifdef HW_FP8
    int w = __builtin_amdgcn_cvt_pk_fp8_f32(a, b, 0, false);
    w = __builtin_amdgcn_cvt_pk_fp8_f32(c, d, w, true);
    return (unsigned)w;
#else
    return fp8_of(a) | (fp8_of(b) << 8) | (fp8_of(c) << 16) | (fp8_of(d) << 24);
#endif
}
__device__ __forceinline__ fv2 f8lo(unsigned w) {
#ifdef HW_FP8
    return __builtin_amdgcn_cvt_pk_f32_fp8((int)w, false);
#else
    fv2 t; t.x = fp8_to_f(w & 0xFFu); t.y = fp8_to_f((w >> 8) & 0xFFu); return t;
#endif
}
__device__ __forceinline__ fv2 f8hi(unsigned w) {
#ifdef HW_FP8
    return __builtin_amdgcn_cvt_pk_f32_fp8((int)w, true);
#else
    fv2 t; t.x = fp8_to_f((w >> 16) & 0xFFu); t.y = fp8_to_f(w >> 24); return t;
#endif
}

// ---------------- init ----------------

__global__ void zero4_kernel(int4* p, int nvec) {
    int i = blockIdx.x * blockDim.x + threadIdx.x;
    if (i < nvec) p[i] = make_int4(0, 0, 0, 0);
}

// ---------------- binA: LDS-staged bucket sort with ordered copy ----------------

__global__ void binA_kernel(const int* __restrict__ src, const int* __restrict__ dst,
                            int* __restrict__ bucketCur, int* __restrict__ stage) {
    __shared__ int lcnt[NBUCK + 1];
    __shared__ int boff[NBUCK + 1];
    __shared__ int gbase[NBUCK + 1];
    __shared__ int cur[NBUCK + 1];
    __shared__ int ssum[256];
    __shared__ int packed[CHUNK];
    __shared__ unsigned short bof[CHUNK];
    int tid = threadIdx.x;
    int beg = blockIdx.x * CHUNK;
    int end = beg + CHUNK; if (end > NEDGES) end = NEDGES;
    int cnt = end - beg;

    for (int i = tid; i <= NBUCK; i += 256) lcnt[i] = 0;
    __syncthreads();

    int ent[16];
    int bk[16];
#pragma unroll
    for (int it = 0; it < 4; ++it) {
        int e0 = beg + tid * 4 + it * 1024;
        if (e0 < end) {
            iv4 d4 = __builtin_nontemporal_load((const iv4*)(dst + e0));
            iv4 s4 = __builtin_nontemporal_load((const iv4*)(src + e0));
            int b;
            b = d4.x / BNODES; ent[it*4+0] = s4.x | ((d4.x - b*BNODES) << 17); bk[it*4+0] = b; atomicAdd(&lcnt[b], 1);
            b = d4.y / BNODES; ent[it*4+1] = s4.y | ((d4.y - b*BNODES) << 17); bk[it*4+1] = b; atomicAdd(&lcnt[b], 1);
            b = d4.z / BNODES; ent[it*4+2] = s4.z | ((d4.z - b*BNODES) << 17); bk[it*4+2] = b; atomicAdd(&lcnt[b], 1);
            b = d4.w / BNODES; ent[it*4+3] = s4.w | ((d4.w - b*BNODES) << 17); bk[it*4+3] = b; atomicAdd(&lcnt[b], 1);
        } else {
            bk[it*4+0] = -1; bk[it*4+1] = -1; bk[it*4+2] = -1; bk[it*4+3] = -1;
            ent[it*4+0] = 0; ent[it*4+1] = 0; ent[it*4+2] = 0; ent[it*4+3] = 0;
        }
    }
    __syncthreads();

    int b0 = 2 * tid, b1 = 2 * tid + 1;
    int c0 = lcnt[b0];
    int c1 = (b1 < NBUCK) ? lcnt[b1] : 0;
    int sum = c0 + c1;
    ssum[tid] = sum;
    __syncthreads();
    for (int o = 1; o < 256; o <<= 1) {
        int t = (tid >= o) ? ssum[tid - o] : 0;
        __syncthreads();
        ssum[tid] += t;
        __syncthreads();
    }
    int excl = ssum[tid] - sum;
    boff[b0] = excl; cur[b0] = excl;
    if (b1 < NBUCK) { boff[b1] = excl + c0; cur[b1] = excl + c0; }
    if (c0 > 0) gbase[b0] = atomicAdd(&bucketCur[b0], c0);
    if (b1 < NBUCK && c1 > 0) gbase[b1] = atomicAdd(&bucketCur[b1], c1);
    __syncthreads();

#pragma unroll
    for (int k = 0; k < 16; ++k) {
        int b = bk[k];
        if (b >= 0) {
            int p = atomicAdd(&cur[b], 1);
            packed[p] = ent[k];
            bof[p] = (unsigned short)b;
        }
    }
    __syncthreads();

    for (int i = tid; i < cnt; i += 256) {
        int b = bof[i];
        int addr = b * SCAP + gbase[b] + (i - boff[b]);
        stage[addr] = packed[i];
    }
}

// ---------------- scanE ----------------

__global__ void scanE_kernel(const int* __restrict__ bucketCur, int* __restrict__ ebase) {
    int lane = threadIdx.x;          // 64 lanes
    int run = 0;
    for (int base = 0; base < NBUCK; base += 64) {
        int idx = base + lane;
        int own = (idx < NBUCK) ? bucketCur[idx] : 0;
        int v = own;
        for (int o = 1; o < 64; o <<= 1) {
            int t = __shfl_up(v, o, 64);
            if (lane >= o) v += t;
        }
        if (idx < NBUCK) ebase[idx] = run + v - own;
        run += __shfl(v, 63, 64);
    }
}

// ---------------- binB: per-bucket fine sort + rowptr/rowend/dinv/xs ----------------

__global__ void binB_kernel(const int* __restrict__ bucketCur, const int* __restrict__ ebase,
                            const int* __restrict__ stage, const float2* __restrict__ x,
                            int* __restrict__ entries, int* __restrict__ rowptr,
                            int* __restrict__ rowend, float* __restrict__ dinv,
                            unsigned* __restrict__ xs) {
    __shared__ int s[256];
    __shared__ int ncur[256];
    __shared__ float ndinv[256];
    int b = blockIdx.x;
    int cntE = bucketCur[b];
    int eb = ebase[b];
    int nlo = b * BNODES;
    int nn = NNODES - nlo; if (nn > BNODES) nn = BNODES;
    int sb = b * SCAP;
    int tid = threadIdx.x;

    s[tid] = 0;
    __syncthreads();
    for (int e = tid; e < cntE; e += 256) {
        unsigned w = (unsigned)stage[sb + e];
        atomicAdd(&s[w >> 17], 1);
    }
    __syncthreads();
    int v = s[tid];
    for (int o = 1; o < 256; o <<= 1) {
        int t = (tid >= o) ? s[tid - o] : 0;
        __syncthreads();
        s[tid] += t;
        __syncthreads();
    }
    int excl = s[tid] - v;
    ncur[tid] = excl;
    if (tid < nn) {
        rowptr[nlo + tid] = eb + excl;
        rowend[nlo + tid] = eb + excl + v;
        float di = rsqrtf((float)(v + 1));   // +1 self-loop
        dinv[nlo + tid] = di;
        ndinv[tid] = di;
    }
    __syncthreads();
    for (int i = tid; i < nn * 8; i += 256) {
        int node = i >> 3, w = i & 7;
        float2 v2 = x[(size_t)(nlo + node) * 8 + w];
        float di = ndinv[node];
        xs[(nlo + node) * 8 + w] = bf16pair(v2.x * di, v2.y * di);
    }
    for (int e = tid; e < cntE; e += 256) {
        unsigned w = (unsigned)stage[sb + e];
        int dl = w >> 17;
        int slot = atomicAdd(&ncur[dl], 1);
        entries[eb + slot] = (int)(w & 0x1FFFFu);
    }
}

// ---------------- gather layer 1: 8 lanes/node (4-way edge split x 2-way feature split) ----------------

__device__ __forceinline__ void acc_bf(unsigned u, fv2& a) {
    fv2 t; t.x = bflo(u); t.y = bfhi(u);
    a += t;
}
#define ACCX4(V) { acc_bf((V).x, acc0); acc_bf((V).y, acc1); acc_bf((V).z, acc2); acc_bf((V).w, acc3); }
#define QRED(a) { a.x += __shfl_xor(a.x, 2); a.y += __shfl_xor(a.y, 2); \
                  a.x += __shfl_xor(a.x, 4); a.y += __shfl_xor(a.y, 4); }

__global__ void __launch_bounds__(256) gatherX_kernel(const int* __restrict__ entries,
        const int* __restrict__ rowptr, const int* __restrict__ rowend,
        const float* __restrict__ dinv, const uint4* __restrict__ xsv,
        float4* __restrict__ agg) {
    int t = blockIdx.x * 256 + threadIdx.x;
    int n = t >> 3, lane = t & 7;
    int half = lane & 1, quad = lane >> 1;
    int beg = rowptr[n], end = rowend[n];
    fv2 acc0 = {0.f, 0.f}, acc1 = {0.f, 0.f}, acc2 = {0.f, 0.f}, acc3 = {0.f, 0.f};
    if (quad == 0) {
        uint4 sv = xsv[n * 2 + half];
        ACCX4(sv);
    }

    int nb = (end - beg) >> 4;               // full 16-edge blocks
    const int* ep = entries + beg + (quad << 2);
    iv4 e = {0, 0, 0, 0};
    if (nb > 0) __builtin_memcpy(&e, ep, 16);
    for (int i = 1; i <= nb; ++i) {
        iv4 f = e;
        if (i < nb) __builtin_memcpy(&e, ep + (i << 4), 16);
        uint4 v0 = xsv[f.x * 2 + half];
        uint4 v1 = xsv[f.y * 2 + half];
        uint4 v2 = xsv[f.z * 2 + half];
        uint4 v3 = xsv[f.w * 2 + half];
        ACCX4(v0); ACCX4(v1); ACCX4(v2); ACCX4(v3);
    }
    // tail: < 16 remaining edges, quad q covers positions [q*4, q*4+4)
    int tp = beg + (nb << 4) + (quad << 2);
#pragma unroll
    for (int j = 0; j < 4; ++j) {
        if (tp + j < end) {
            int ee = entries[tp + j];
            uint4 v = xsv[ee * 2 + half];
            ACCX4(v);
        }
    }

    QRED(acc0); QRED(acc1); QRED(acc2); QRED(acc3);

    if (quad == 0) {
        float di = dinv[n];
        float4 o0, o1;
        o0.x = acc0.x * di; o0.y = acc0.y * di; o0.z = acc1.x * di; o0.w = acc1.y * di;
        o1.x = acc2.x * di; o1.y = acc2.y * di; o1.z = acc3.x * di; o1.w = acc3.y * di;
        agg[n * 4 + half * 2 + 0] = o0;
        agg[n * 4 + half * 2 + 1] = o1;
    }
}

// ---------------- node MLP (separate, float4 LDS access) ----------------

__global__ void __launch_bounds__(256) mlp_kernel(const float4* __restrict__ agg,
        const float* __restrict__ dinv,
        const float* __restrict__ W1, const float* __restrict__ b1,
        const float* __restrict__ W2, unsigned* __restrict__ hm2f) {
    __shared__ __align__(16) float w1s[16 * 64];   // 4 KB
    __shared__ __align__(16) float w2s[64 * 32];   // 8 KB
    __shared__ float bb1[64];
    __shared__ __align__(16) float h1s[32][68];    // 8.5 KB, pad 68 keeps f4 align + spread
    int tid = threadIdx.x;
    for (int i = tid; i < 16 * 64; i += 256) w1s[i] = W1[i];
    for (int i = tid; i < 64 * 32; i += 256) w2s[i] = W2[i];
    if (tid < 64) bb1[tid] = b1[tid];

    int nl = tid >> 3, lane = tid & 7;
    int n = blockIdx.x * 32 + nl;
    const float4* ag = agg + n * 4;
    float4 A0 = ag[0], A1 = ag[1], A2 = ag[2], A3 = ag[3];
    float a[16] = {A0.x, A0.y, A0.z, A0.w, A1.x, A1.y, A1.z, A1.w,
                   A2.x, A2.y, A2.z, A2.w, A3.x, A3.y, A3.z, A3.w};
    __syncthreads();

    // phase B: h1[j] for j = lane*8 .. +7
    {
        int j0 = lane * 8;
        float h[8];
#pragma unroll
        for (int jj = 0; jj < 8; ++jj) h[jj] = bb1[j0 + jj];
#pragma unroll
        for (int k = 0; k < 16; ++k) {
            const float4* wr = (const float4*)(w1s + k * 64 + j0);
            float4 wa = wr[0], wb = wr[1];
            float av = a[k];
            h[0] += av * wa.x; h[1] += av * wa.y; h[2] += av * wa.z; h[3] += av * wa.w;
            h[4] += av * wb.x; h[5] += av * wb.y; h[6] += av * wb.z; h[7] += av * wb.w;
        }
        float4 r0, r1;
        r0.x = fmaxf(h[0], 0.f); r0.y = fmaxf(h[1], 0.f); r0.z = fmaxf(h[2], 0.f); r0.w = fmaxf(h[3], 0.f);
        r1.x = fmaxf(h[4], 0.f); r1.y = fmaxf(h[5], 0.f); r1.z = fmaxf(h[6], 0.f); r1.w = fmaxf(h[7], 0.f);
        float4* hw = (float4*)(&h1s[nl][j0]);
        hw[0] = r0; hw[1] = r1;
    }
    __syncthreads();

    // phase C: h2[j] for j = lane*4 .. +3, pack fp8 word (strict FMA order preserved)
    {
        int j0 = lane * 4;
        float c0 = 0.f, c1 = 0.f, c2 = 0.f, c3 = 0.f;
#pragma unroll
        for (int k = 0; k < 64; k += 4) {
            float4 hv = *(const float4*)(&h1s[nl][k]);
            float4 w0 = *(const float4*)(w2s + (k + 0) * 32 + j0);
            float4 w1v = *(const float4*)(w2s + (k + 1) * 32 + j0);
            float4 w2v = *(const float4*)(w2s + (k + 2) * 32 + j0);
            float4 w3 = *(const float4*)(w2s + (k + 3) * 32 + j0);
            c0 += hv.x * w0.x; c1 += hv.x * w0.y; c2 += hv.x * w0.z; c3 += hv.x * w0.w;
            c0 += hv.y * w1v.x; c1 += hv.y * w1v.y; c2 += hv.y * w1v.z; c3 += hv.y * w1v.w;
            c0 += hv.z * w2v.x; c1 += hv.z * w2v.y; c2 += hv.z * w2v.z; c3 += hv.z * w2v.w;
            c0 += hv.w * w3.x; c1 += hv.w * w3.y; c2 += hv.w * w3.z; c3 += hv.w * w3.w;
        }
        float sc = dinv[n] * 64.f;                  // x64 pre-scale for fp8
        hm2f[n * 8 + lane] = fp8x4_pack(c0 * sc, c1 * sc, c2 * sc, c3 * sc);
    }
}

// ---------------- gather layer 2 + pool: 8 lanes/node, 16B fp8 gathers ----------------

#define ACCH4(V) { q0lo += f8lo((V).x); q0hi += f8hi((V).x); \
                   q1lo += f8lo((V).y); q1hi += f8hi((V).y); \
                   q2lo += f8lo((V).z); q2hi += f8hi((V).z); \
                   q3lo += f8lo((V).w); q3hi += f8hi((V).w); }

__global__ void __launch_bounds__(256) gatherH_pool_kernel(const int* __restrict__ entries,
        const int* __restrict__ rowptr, const int* __restrict__ rowend,
        const float* __restrict__ dinv, const uint4* __restrict__ hm4,
        const float4* __restrict__ b2, const int* __restrict__ batch,
        float* __restrict__ psum, float* __restrict__ pcnt) {
    __shared__ float lps[8][32];
    __shared__ float lpc[8];
    int tid = threadIdx.x;
    ((float*)lps)[tid] = 0.f;
    if (tid < 8) lpc[tid] = 0.f;
    __syncthreads();

    int t = blockIdx.x * 256 + tid;
    int n = t >> 3, lane = t & 7;
    int half = lane & 1, quad = lane >> 1;
    int g0 = batch[blockIdx.x * 32];
    int beg = rowptr[n], end = rowend[n];
    fv2 q0lo = {0.f,0.f}, q0hi = {0.f,0.f}, q1lo = {0.f,0.f}, q1hi = {0.f,0.f},
        q2lo = {0.f,0.f}, q2hi = {0.f,0.f}, q3lo = {0.f,0.f}, q3hi = {0.f,0.f};
    if (quad == 0) {
        uint4 sv = hm4[n * 2 + half];
        ACCH4(sv);
    }

    int nb = (end - beg) >> 4;
    const int* ep = entries + beg + (quad << 2);
    iv4 e = {0, 0, 0, 0};
    if (nb > 0) __builtin_memcpy(&e, ep, 16);
    for (int i = 1; i <= nb; ++i) {
        iv4 f = e;
        if (i < nb) __builtin_memcpy(&e, ep + (i << 4), 16);
        uint4 v0 = hm4[f.x * 2 + half];
        uint4 v1 = hm4[f.y * 2 + half];
        uint4 v2 = hm4[f.z * 2 + half];
        uint4 v3 = hm4[f.w * 2 + half];
        ACCH4(v0); ACCH4(v1); ACCH4(v2); ACCH4(v3);
    }
    int tp = beg + (nb << 4) + (quad << 2);
#pragma unroll
    for (int j = 0; j < 4; ++j) {
        if (tp + j < end) {
            int ee = entries[tp + j];
            uint4 v = hm4[ee * 2 + half];
            ACCH4(v);
        }
    }

    QRED(q0lo); QRED(q0hi); QRED(q1lo); QRED(q1hi);
    QRED(q2lo); QRED(q2hi); QRED(q3lo); QRED(q3hi);

    if (quad == 0) {
        float sc = dinv[n] * (1.0f / 64.f);         // undo x64 pre-scale
        float4 bv0 = b2[half * 4 + 0], bv1 = b2[half * 4 + 1],
               bv2 = b2[half * 4 + 2], bv3 = b2[half * 4 + 3];
        float vv[16];
        vv[0]  = fmaxf(q0lo.x * sc + bv0.x, 0.f);
        vv[1]  = fmaxf(q0lo.y * sc + bv0.y, 0.f);
        vv[2]  = fmaxf(q0hi.x * sc + bv0.z, 0.f);
        vv[3]  = fmaxf(q0hi.y * sc + bv0.w, 0.f);
        vv[4]  = fmaxf(q1lo.x * sc + bv1.x, 0.f);
        vv[5]  = fmaxf(q1lo.y * sc + bv1.y, 0.f);
        vv[6]  = fmaxf(q1hi.x * sc + bv1.z, 0.f);
        vv[7]  = fmaxf(q1hi.y * sc + bv1.w, 0.f);
        vv[8]  = fmaxf(q2lo.x * sc + bv2.x, 0.f);
        vv[9]  = fmaxf(q2lo.y * sc + bv2.y, 0.f);
        vv[10] = fmaxf(q2hi.x * sc + bv2.z, 0.f);
        vv[11] = fmaxf(q2hi.y * sc + bv2.w, 0.f);
        vv[12] = fmaxf(q3lo.x * sc + bv3.x, 0.f);
        vv[13] = fmaxf(q3lo.y * sc + bv3.y, 0.f);
        vv[14] = fmaxf(q3hi.x * sc + bv3.z, 0.f);
        vv[15] = fmaxf(q3hi.y * sc + bv3.w, 0.f);

        int g = batch[n], gr = g - g0;
        if (gr < 8) {
            float* pg = &lps[gr][half * 16];
#pragma unroll
            for (int k2 = 0; k2 < 16; ++k2) atomicAdd(pg + k2, vv[k2]);
            if (lane == 0) atomicAdd(&lpc[gr], 1.0f);
        } else {
            float* pg = psum + g * 32 + half * 16;
#pragma unroll
            for (int k2 = 0; k2 < 16; ++k2) atomicAdd(pg + k2, vv[k2]);
            if (lane == 0) atomicAdd(&pcnt[g], 1.0f);
        }
    }
    __syncthreads();
    int grf = tid >> 5, f = tid & 31;
    float v = lps[grf][f];
    if (v != 0.f) atomicAdd(&psum[(g0 + grf) * 32 + f], v);
    if (f == 0) {
        float c = lpc[grf];
        if (c != 0.f) atomicAdd(&pcnt[g0 + grf], c);
    }
}

// ---------------- head ----------------

__global__ void head_kernel(const float* __restrict__ psum, const float* __restrict__ pcnt,
                            const float* __restrict__ fc1W, const float* __restrict__ fc1b,
                            const float* __restrict__ fc2W, const float* __restrict__ fc2b,
                            float* __restrict__ out) {
    int g = blockIdx.x * blockDim.x + threadIdx.x;
    if (g >= NGRAPHS) return;
    float inv = 1.0f / fmaxf(pcnt[g], 1.0f);
    float gv[32];
#pragma unroll
    for (int k = 0; k < 32; ++k) gv[k] = psum[g * 32 + k] * inv;
    float o = fc2b[0];
#pragma unroll
    for (int j = 0; j < 16; ++j) {
        float h = fc1b[j];
#pragma unroll
        for (int k = 0; k < 32; ++k) h += gv[k] * fc1W[k * 16 + j];
        h = fmaxf(h, 0.f);
        o += h * fc2W[j];
    }
    out[g] = 1.0f / (1.0f + expf(-o));
}

// ---------------- launch ----------------

extern "C" void kernel_launch(void* const* d_in, const int* in_sizes, int n_in,
                              void* d_out, int out_size, void* d_ws, size_t ws_size,
                              hipStream_t stream) {
    const float* x    = (const float*)d_in[0];
    const int*   ei   = (const int*)d_in[1];
    const int*   batch= (const int*)d_in[2];
    const float* W1   = (const float*)d_in[3];
    const float* b1   = (const float*)d_in[4];
    const float* W2   = (const float*)d_in[5];
    const float* b2   = (const float*)d_in[6];
    const float* fc1W = (const float*)d_in[7];
    const float* fc1b = (const float*)d_in[8];
    const float* fc2W = (const float*)d_in[9];
    const float* fc2b = (const float*)d_in[10];
    float* out = (float*)d_out;

    const int* src = ei;
    const int* dst = ei + NEDGES;

    char* wsb = (char*)d_ws;
    int*      bucketCur = (int*)wsb;                 // 2048 B  } zeroed span
    float*    psum      = (float*)(wsb + 2048);      // 131072  }
    float*    pcnt      = (float*)(wsb + 133120);    // 4096    }  -> zero 137216 B
    int*      ebase     = (int*)(wsb + 137216);      // 2048
    float*    dinv      = (float*)(wsb + 139264);    // 400000
    int*      rowptr    = (int*)(wsb + 539264);      // 400000
    int*      rowend    = (int*)(wsb + 939264);      // 400000
    int*      stage     = (int*)(wsb + 1339392);     // 25.1 MB
    int*      entries   = (int*)(wsb + 26456064);    // 12.8 MB
    unsigned* xs        = (unsigned*)(wsb + 39256064);   // 3.2 MB (bf16x2)
    unsigned* hm2f      = (unsigned*)(wsb + 42456064);   // 3.2 MB (fp8, 32 B rows)
    // agg (f32 layer-1 aggregate, 6.4 MB) aliases stage — stage is dead after binB
    float4*   agg       = (float4*)(wsb + 1339392);

    const int B = 256;
    zero4_kernel<<<(8576 + B - 1) / B, B, 0, stream>>>((int4*)wsb, 8576);

    binA_kernel<<<NCHUNKS, B, 0, stream>>>(src, dst, bucketCur, stage);
    scanE_kernel<<<1, 64, 0, stream>>>(bucketCur, ebase);
    binB_kernel<<<NBUCK, B, 0, stream>>>(bucketCur, ebase, stage, (const float2*)x,
                                         entries, rowptr, rowend, dinv, xs);

    const int GTH = NNODES * 8 / B;                  // 3125
    gatherX_kernel<<<GTH, B, 0, stream>>>(entries, rowptr, rowend, dinv,
                                          (const uint4*)xs, agg);
    mlp_kernel<<<NNODES / 32, B, 0, stream>>>((const float4*)agg, dinv, W1, b1, W2, hm2f);
    gatherH_pool_kernel<<<GTH, B, 0, stream>>>(entries, rowptr, rowend, dinv,
                                               (const uint4*)hm2f, (const float4*)b2,
                                               batch, psum, pcnt);
    head_kernel<<<(NGRAPHS + B - 1) / B, B, 0, stream>>>(psum, pcnt, fc1W, fc1b, fc2W, fc2b, out);
}